// Round 7
// baseline (308.885 us; speedup 1.0000x reference)
//
#include <hip/hip_runtime.h>
#include <hip/hip_bf16.h>
#include <stdint.h>

#define D_MODEL 1024
#define SEQ     2048
#define NH      16
#define DK      64
#define PSTR    72   // P LDS row stride (u16); 144B row = 16B-aligned

typedef __bf16 bf16x8 __attribute__((ext_vector_type(8)));
typedef float  f32x4  __attribute__((ext_vector_type(4)));
typedef unsigned short u16;

#define CFENCE() asm volatile("" ::: "memory")

__device__ __forceinline__ u16 f2bf(float f) {
    uint32_t u = __float_as_uint(f);
    u += 0x7FFFu + ((u >> 16) & 1u);
    return (u16)(u >> 16);
}

// async global->LDS, 16B per lane; lds dest = uniform base + lane*16 (m104)
__device__ __forceinline__ void gl2lds16(const u16* g, u16* l) {
    __builtin_amdgcn_global_load_lds(
        (const __attribute__((address_space(1))) uint32_t*)g,
        (__attribute__((address_space(3))) uint32_t*)l, 16, 0, 0);
}

__global__ __launch_bounds__(256) void cvt_kernel(const float* __restrict__ src,
                                                  u16* __restrict__ dst, int n4) {
    int i = blockIdx.x * blockDim.x + threadIdx.x;
    if (i >= n4) return;
    float4 v = reinterpret_cast<const float4*>(src)[i];
    ushort4 o;
    o.x = f2bf(v.x); o.y = f2bf(v.y); o.z = f2bf(v.z); o.w = f2bf(v.w);
    reinterpret_cast<ushort4*>(dst)[i] = o;
}

__global__ __launch_bounds__(256) void cvt4_kernel(
    const float* __restrict__ s0, const float* __restrict__ s1,
    const float* __restrict__ s2, const float* __restrict__ s3,
    u16* __restrict__ d0, u16* __restrict__ d1,
    u16* __restrict__ d2, u16* __restrict__ d3, int n4) {
    int z = blockIdx.y;
    const float* s = (z == 0) ? s0 : (z == 1) ? s1 : (z == 2) ? s2 : s3;
    u16* d = (z == 0) ? d0 : (z == 1) ? d1 : (z == 2) ? d2 : d3;
    int i = blockIdx.x * blockDim.x + threadIdx.x;
    if (i >= n4) return;
    float4 v = reinterpret_cast<const float4*>(s)[i];
    ushort4 o;
    o.x = f2bf(v.x); o.y = f2bf(v.y); o.z = f2bf(v.z); o.w = f2bf(v.w);
    reinterpret_cast<ushort4*>(d)[i] = o;
}

// ---------------------------------------------------------------------------
// 128x128 tile GEMM body (legacy 2-barrier structure) — still used by out_gemm.
// ---------------------------------------------------------------------------
__device__ __forceinline__ void gemm128_body(const u16* __restrict__ Ag,
                                             const u16* __restrict__ Bg,
                                             u16* As, u16* Bs, f32x4 acc[4][4]) {
    const int K = D_MODEL;
    int tid = threadIdx.x, wave = tid >> 6, lane = tid & 63;
    int l15 = lane & 15, quad = lane >> 4;
    int srow = lane >> 2;            // 0..15
    int scol = (lane & 3) * 8;       // 0,8,16,24
    int arg4 = (wave >> 1) * 4;      // A row-group base (16-row units)
    int brg4 = (wave & 1) * 4;
#pragma unroll 1
    for (int kc = 0; kc < K; kc += 64) {
        __syncthreads();             // WAR: prev compute's reads done everywhere
#pragma unroll
        for (int j = 0; j < 4; ++j) {
            int p = wave * 4 + j;    // page 0..15
            int rg = p >> 1, h = p & 1;
            int row = rg * 16 + srow;
            int col = kc + h * 32 + scol;
            gl2lds16(Ag + row * K + col, As + p * 512);
            gl2lds16(Bg + row * K + col, Bs + p * 512);
        }
        __syncthreads();             // RAW: all stages landed (vmcnt drained)
#pragma unroll
        for (int h = 0; h < 2; ++h) {
            bf16x8 af[4], bfr[4];
#pragma unroll
            for (int s = 0; s < 4; ++s) {
                af[s]  = *reinterpret_cast<const bf16x8*>(
                    As + ((arg4 + s) * 2 + h) * 512 + l15 * 32 + quad * 8);
                bfr[s] = *reinterpret_cast<const bf16x8*>(
                    Bs + ((brg4 + s) * 2 + h) * 512 + l15 * 32 + quad * 8);
            }
#pragma unroll
            for (int ms = 0; ms < 4; ++ms)
#pragma unroll
                for (int ns = 0; ns < 4; ++ns)
                    acc[ms][ns] = __builtin_amdgcn_mfma_f32_16x16x32_bf16(
                        af[ms], bfr[ns], acc[ms][ns], 0, 0, 0);
        }
    }
}

// ---------------------------------------------------------------------------
// QKV projection — UNCHANGED from R6 (measured best: 89.5us, WRITE=48MiB
// ideal, conflicts ~0 K-loop). 256x256 tile, 8 waves, 4-phase/K-tile,
// R3 stage map, counted vmcnt(2), both-sides swizzle, coalesced LDS-transpose
// epilogue (fully unrolled; acc never runtime-indexed).
// ---------------------------------------------------------------------------
__device__ __forceinline__ void stage_half(const u16* __restrict__ gb, u16* ls,
                                           int w2, int srow, int scol) {
#pragma unroll
    for (int i = 0; i < 2; ++i)
        gl2lds16(gb + ((w2 + i) * 8 + srow) * D_MODEL + scol,
                 ls + (w2 + i) * 512);
}

__global__ __launch_bounds__(512, 2) void qkv_gemm256(
    const u16* __restrict__ xb,
    const u16* __restrict__ Wq, const u16* __restrict__ Wk, const u16* __restrict__ Wv,
    const float* __restrict__ bq, const float* __restrict__ bk, const float* __restrict__ bv,
    u16* __restrict__ qo, u16* __restrict__ ko, u16* __restrict__ vto) {
    __shared__ __align__(16) u16 smA[2][2][8192];   // [buf][half][128*64]
    __shared__ __align__(16) u16 smB[2][2][8192];
    int z = blockIdx.z;
    const u16* W = (z == 0) ? Wq : (z == 1) ? Wk : Wv;
    const float* bias = (z == 0) ? bq : (z == 1) ? bk : bv;
    int tid = threadIdx.x;
    int lane = tid & 63, wave = tid >> 6;
    int l15 = lane & 15, quad = lane >> 4;
    int wr = wave >> 2, wc = wave & 3;       // 2 x 4 wave grid
    int w2 = wave * 2;
    const u16* Abase = xb + (size_t)blockIdx.x * 256 * D_MODEL;
    const u16* Bbase = W + (size_t)blockIdx.y * 256 * D_MODEL;

    // staging: linear LDS dest; inverse-swizzled per-lane GLOBAL source.
    int srow = lane >> 3;                        // row within 8-row page
    int scol = ((lane & 7) ^ (lane >> 3)) * 8;   // u16: 16*((L&7)^(L>>3)) bytes
    // frag reads: col ^ (row&7)<<4, row&7 == l15&7 for all fragments here
    int xb_ = (l15 & 7) << 4;                    // byte-domain XOR
    int c0 = ((quad * 16) ^ xb_) >> 1;           // u16 col offset, ks=0
    int c1 = ((64 + quad * 16) ^ xb_) >> 1;      // u16 col offset, ks=1
    int rb0 = (wc & 1) * 64;                     // B row base within its half

    f32x4 acc[8][4];
#pragma unroll
    for (int m = 0; m < 8; ++m)
#pragma unroll
        for (int n = 0; n < 4; ++n) acc[m][n] = (f32x4){0.f, 0.f, 0.f, 0.f};

    // prologue: tile0 complete + A0(1); keep A0(1) in flight (vmcnt(2))
    stage_half(Abase, &smA[0][0][0], w2, srow, scol);                    // A0(0)
    stage_half(Abase + 128 * D_MODEL, &smA[0][1][0], w2, srow, scol);    // A1(0)
    stage_half(Bbase, &smB[0][0][0], w2, srow, scol);                    // B0(0)
    stage_half(Bbase + 128 * D_MODEL, &smB[0][1][0], w2, srow, scol);    // B1(0)
    stage_half(Abase + 64, &smA[1][0][0], w2, srow, scol);               // A0(1)
    asm volatile("s_waitcnt vmcnt(2)" ::: "memory");
    __builtin_amdgcn_s_barrier();
    CFENCE();

#pragma unroll 1
    for (int t = 0; t < 16; ++t) {
        const int p = t & 1;
        const u16* As = &smA[p][wr][0];
        const u16* Bs = &smB[p][wc >> 1][0];
        bf16x8 af[4][2], bfr[4][2];

        // ---- P1: read af m0-3 + bfr n0-1; stage A1(t+1); mfma m0-3 x n0-1
#pragma unroll
        for (int m = 0; m < 4; ++m) {
            af[m][0] = *reinterpret_cast<const bf16x8*>(As + (m * 16 + l15) * 64 + c0);
            af[m][1] = *reinterpret_cast<const bf16x8*>(As + (m * 16 + l15) * 64 + c1);
        }
#pragma unroll
        for (int nn = 0; nn < 2; ++nn) {
            bfr[nn][0] = *reinterpret_cast<const bf16x8*>(Bs + (rb0 + nn * 16 + l15) * 64 + c0);
            bfr[nn][1] = *reinterpret_cast<const bf16x8*>(Bs + (rb0 + nn * 16 + l15) * 64 + c1);
        }
        if (t < 15) stage_half(Abase + 128 * D_MODEL + (t + 1) * 64,
                               &smA[(t + 1) & 1][1][0], w2, srow, scol);
        CFENCE(); __builtin_amdgcn_s_barrier(); CFENCE();
        __builtin_amdgcn_s_setprio(1);
#pragma unroll
        for (int m = 0; m < 4; ++m)
#pragma unroll
            for (int nn = 0; nn < 2; ++nn) {
                acc[m][nn] = __builtin_amdgcn_mfma_f32_16x16x32_bf16(af[m][0], bfr[nn][0], acc[m][nn], 0, 0, 0);
                acc[m][nn] = __builtin_amdgcn_mfma_f32_16x16x32_bf16(af[m][1], bfr[nn][1], acc[m][nn], 0, 0, 0);
            }
        __builtin_amdgcn_s_setprio(0);
        CFENCE(); __builtin_amdgcn_s_barrier(); CFENCE();

        // ---- P2: read bfr n2-3; stage B0(t+1); mfma m0-3 x n2-3
#pragma unroll
        for (int nn = 0; nn < 2; ++nn) {
            bfr[2 + nn][0] = *reinterpret_cast<const bf16x8*>(Bs + (rb0 + (2 + nn) * 16 + l15) * 64 + c0);
            bfr[2 + nn][1] = *reinterpret_cast<const bf16x8*>(Bs + (rb0 + (2 + nn) * 16 + l15) * 64 + c1);
        }
        if (t < 15) stage_half(Bbase + (t + 1) * 64,
                               &smB[(t + 1) & 1][0][0], w2, srow, scol);
        CFENCE(); __builtin_amdgcn_s_barrier(); CFENCE();
        __builtin_amdgcn_s_setprio(1);
#pragma unroll
        for (int m = 0; m < 4; ++m)
#pragma unroll
            for (int nn = 0; nn < 2; ++nn) {
                acc[m][2 + nn] = __builtin_amdgcn_mfma_f32_16x16x32_bf16(af[m][0], bfr[2 + nn][0], acc[m][2 + nn], 0, 0, 0);
                acc[m][2 + nn] = __builtin_amdgcn_mfma_f32_16x16x32_bf16(af[m][1], bfr[2 + nn][1], acc[m][2 + nn], 0, 0, 0);
            }
        __builtin_amdgcn_s_setprio(0);
        CFENCE(); __builtin_amdgcn_s_barrier(); CFENCE();

        // ---- P3: read af m4-7 (reuse regs); stage B1(t+1); mfma m4-7 x n0-1
#pragma unroll
        for (int m = 0; m < 4; ++m) {
            af[m][0] = *reinterpret_cast<const bf16x8*>(As + ((m + 4) * 16 + l15) * 64 + c0);
            af[m][1] = *reinterpret_cast<const bf16x8*>(As + ((m + 4) * 16 + l15) * 64 + c1);
        }
        if (t < 15) stage_half(Bbase + 128 * D_MODEL + (t + 1) * 64,
                               &smB[(t + 1) & 1][1][0], w2, srow, scol);
        CFENCE(); __builtin_amdgcn_s_barrier(); CFENCE();
        __builtin_amdgcn_s_setprio(1);
#pragma unroll
        for (int m = 0; m < 4; ++m)
#pragma unroll
            for (int nn = 0; nn < 2; ++nn) {
                acc[4 + m][nn] = __builtin_amdgcn_mfma_f32_16x16x32_bf16(af[m][0], bfr[nn][0], acc[4 + m][nn], 0, 0, 0);
                acc[4 + m][nn] = __builtin_amdgcn_mfma_f32_16x16x32_bf16(af[m][1], bfr[nn][1], acc[4 + m][nn], 0, 0, 0);
            }
        __builtin_amdgcn_s_setprio(0);
        CFENCE(); __builtin_amdgcn_s_barrier(); CFENCE();

        // ---- P4: no reads; stage A0(t+2); mfma m4-7 x n2-3; vmcnt; barrier
        if (t < 14) stage_half(Abase + (t + 2) * 64,
                               &smA[p][0][0], w2, srow, scol);
        CFENCE(); __builtin_amdgcn_s_barrier(); CFENCE();
        __builtin_amdgcn_s_setprio(1);
#pragma unroll
        for (int m = 0; m < 4; ++m)
#pragma unroll
            for (int nn = 0; nn < 2; ++nn) {
                acc[4 + m][2 + nn] = __builtin_amdgcn_mfma_f32_16x16x32_bf16(af[m][0], bfr[2 + nn][0], acc[4 + m][2 + nn], 0, 0, 0);
                acc[4 + m][2 + nn] = __builtin_amdgcn_mfma_f32_16x16x32_bf16(af[m][1], bfr[2 + nn][1], acc[4 + m][2 + nn], 0, 0, 0);
            }
        __builtin_amdgcn_s_setprio(0);
        if (t < 14) {
            asm volatile("s_waitcnt vmcnt(2)" ::: "memory");   // tile t+1 landed
            __builtin_amdgcn_s_barrier(); CFENCE();
        } else if (t == 14) {
            asm volatile("s_waitcnt vmcnt(0)" ::: "memory");   // tile 15 landed
            __builtin_amdgcn_s_barrier(); CFENCE();
        }
    }

    // Coalesced epilogue via per-wave LDS transpose (fully unrolled).
    int mw = blockIdx.x * 256 + wr * 128;
    int nwb = blockIdx.y * 256 + wc * 64;
    int hq = (nwb >> 6) & (NH - 1);
    const float qscale = 0.125f * 1.4426950408889634f;

    if (z != 2) {
        u16* dst = (z == 0) ? qo : ko;
        float sc = (z == 0) ? qscale : 1.0f;
        u16* tw = &smA[0][0][0] + wave * 1152;     // 16 rows x 72 u16
        float bv0 = bias[nwb + 0 * 16 + l15];
        float bv1 = bias[nwb + 1 * 16 + l15];
        float bv2 = bias[nwb + 2 * 16 + l15];
        float bv3 = bias[nwb + 3 * 16 + l15];
#pragma unroll
        for (int mf = 0; mf < 8; ++mf) {
#pragma unroll
            for (int nf = 0; nf < 4; ++nf) {
                int c = nf * 16 + l15;
                float bv_ = (nf == 0) ? bv0 : (nf == 1) ? bv1 : (nf == 2) ? bv2 : bv3;
#pragma unroll
                for (int r = 0; r < 4; ++r) {
                    int w = quad * 4 + r;
                    tw[w * 72 + (((c >> 3) ^ (w & 7)) << 3) + (c & 7)] =
                        f2bf((acc[mf][nf][r] + bv_) * sc);
                }
            }
            asm volatile("s_waitcnt lgkmcnt(0)" ::: "memory");
#pragma unroll
            for (int i = 0; i < 2; ++i) {
                int w = i * 8 + (lane >> 3);
                bf16x8 vv = *reinterpret_cast<const bf16x8*>(
                    tw + w * 72 + (((lane & 7) ^ (w & 7)) << 3));
                int sg = mw + mf * 16 + w;
                int b = sg >> 11, ss = sg & (SEQ - 1);
                *reinterpret_cast<bf16x8*>(
                    &dst[((b * NH + hq) * SEQ + ss) * DK + (lane & 7) * 8]) = vv;
            }
            asm volatile("s_waitcnt lgkmcnt(0)" ::: "memory");  // WAR before next mf
        }
    } else {
        u16* tw = &smA[0][0][0] + wave * 4608;     // 64 rows x 72 u16
        float bv0 = bias[nwb + 0 * 16 + l15];
        float bv1 = bias[nwb + 1 * 16 + l15];
        float bv2 = bias[nwb + 2 * 16 + l15];
        float bv3 = bias[nwb + 3 * 16 + l15];
#pragma unroll
        for (int half = 0; half < 2; ++half) {
#pragma unroll
            for (int mfi = 0; mfi < 4; ++mfi) {
                int mf = half * 4 + mfi;
#pragma unroll
                for (int nf = 0; nf < 4; ++nf) {
                    int w = nf * 16 + l15;              // d row
                    float bv_ = (nf == 0) ? bv0 : (nf == 1) ? bv1 : (nf == 2) ? bv2 : bv3;
                    int sl = mfi * 16 + quad * 4;       // s_local of elem 0
                    ushort4 pk;
                    pk.x = f2bf(acc[mf][nf][0] + bv_);
                    pk.y = f2bf(acc[mf][nf][1] + bv_);
                    pk.z = f2bf(acc[mf][nf][2] + bv_);
                    pk.w = f2bf(acc[mf][nf][3] + bv_);
                    *reinterpret_cast<ushort4*>(
                        tw + w * 72 + (((sl >> 3) ^ (w & 7)) << 3) + (sl & 7)) = pk;
                }
            }
            asm volatile("s_waitcnt lgkmcnt(0)" ::: "memory");
#pragma unroll
            for (int i = 0; i < 8; ++i) {
                int w = i * 8 + (lane >> 3);            // d
                bf16x8 vv = *reinterpret_cast<const bf16x8*>(
                    tw + w * 72 + (((lane & 7) ^ (w & 7)) << 3));
                int sg = mw + half * 64 + (lane & 7) * 8;
                int b = sg >> 11, ss = sg & (SEQ - 1);
                *reinterpret_cast<bf16x8*>(
                    &vto[((b * NH + hq) * DK + w) * SEQ + ss]) = vv;
            }
            asm volatile("s_waitcnt lgkmcnt(0)" ::: "memory");  // WAR before next half
        }
    }
}

// Output projection: fp32 out = A_bf16 @ Wo^T + bo  (legacy structure)
__global__ __launch_bounds__(256) void out_gemm(
    const u16* __restrict__ ab, const u16* __restrict__ Wo,
    const float* __restrict__ bo, float* __restrict__ out) {
    __shared__ __align__(16) u16 As[16 * 512], Bs[16 * 512];
    int lane = threadIdx.x & 63, wave = threadIdx.x >> 6;
    int l15 = lane & 15, quad = lane >> 4;
    int mw = blockIdx.x * 128 + (wave >> 1) * 64;
    int nw = blockIdx.y * 128 + (wave & 1) * 64;

    f32x4 acc[4][4];
#pragma unroll
    for (int ms = 0; ms < 4; ++ms)
#pragma unroll
        for (int ns = 0; ns < 4; ++ns)
            acc[ms][ns] = (f32x4){0.f, 0.f, 0.f, 0.f};

    gemm128_body(ab + blockIdx.x * 128 * D_MODEL, Wo + blockIdx.y * 128 * D_MODEL,
                 As, Bs, acc);

#pragma unroll
    for (int ns = 0; ns < 4; ++ns) {
        int n = nw + ns * 16 + l15;
        float bv_ = bo[n];
#pragma unroll
        for (int ms = 0; ms < 4; ++ms) {
            int mbase = mw + ms * 16 + quad * 4;
#pragma unroll
            for (int r = 0; r < 4; ++r)
                out[(mbase + r) * D_MODEL + n] = acc[ms][ns][r] + bv_;
        }
    }
}

// ---------------------------------------------------------------------------
// Causal flash attention — R7 REWRITE (attacks the measured serial-drain):
//   Old: per chunk {__syncthreads; stage K/V; __syncthreads(vmcnt(0) drain)}
//        -> every one of 34 chunks eats full L2/HBM latency serially;
//        attn ~= 130us at ~3-4% of its MFMA floor.
//   New: double-buffered K/V + prefetch + counted vmcnt(4):
//     for c: { bar(WAR: c-1 reads done) -> stage(c+1 -> buf^1) ->
//              vmcnt(4) [chunk c's 4 loads, issued one full compute earlier]
//              -> bar(RAW) -> compute(c) }
//     Ledger: enter iter with 4 outstanding (stage c); +4 (stage c+1) = 8;
//     vmcnt(4) drains exactly stage c. Last iter: no stage, vmcnt(0).
//     Masked waves `continue` AFTER both barriers (uniform execution).
//   Single-tile blocks: grid (16,64), t = 15-bx (big tiles dispatched first),
//   launch_bounds(256,3): LDS 51.2KB -> 3 blocks/CU (was 2).
//   Numerics/summation order identical to the proven R5 structure.
// ---------------------------------------------------------------------------
__global__ __launch_bounds__(256, 3) void attn_kernel(
    const u16* __restrict__ Q, const u16* __restrict__ Kc,
    const u16* __restrict__ Vt, u16* __restrict__ ao) {
    __shared__ __align__(16) u16 Ks[2][8 * 512], Vs[2][8 * 512], Plds[4][32 * PSTR];
    int t = 15 - blockIdx.x, bh = blockIdx.y;
    int lane = threadIdx.x & 63, wave = threadIdx.x >> 6;
    int l15 = lane & 15, quad = lane >> 4;
    const u16* Qb = Q + bh * (SEQ * DK);
    const u16* Kb = Kc + bh * (SEQ * DK);
    const u16* Vb = Vt + bh * (DK * SEQ);
    int b = bh >> 4, hh = bh & 15;
    u16* Pw = &Plds[wave][0];

    int q0w = t * 128 + wave * 32;   // this wave's 32 q rows
    int qmax = q0w + 31;

    bf16x8 qf[2][2];
#pragma unroll
    for (int nf = 0; nf < 2; ++nf)
#pragma unroll
        for (int h = 0; h < 2; ++h)
            qf[nf][h] = *reinterpret_cast<const bf16x8*>(
                Qb + (q0w + nf * 16 + l15) * DK + h * 32 + quad * 8);

    f32x4 o[2][4];
#pragma unroll
    for (int ma = 0; ma < 2; ++ma)
#pragma unroll
        for (int nf = 0; nf < 4; ++nf)
            o[ma][nf] = (f32x4){0.f, 0.f, 0.f, 0.f};
    float lsum[2] = {0.f, 0.f};

    int nch = 2 * t + 2;

    // prologue: stage chunk 0 into buf 0 (4 loads/wave)
#pragma unroll
    for (int h = 0; h < 2; ++h) {
        gl2lds16(Kb + (wave * 16 + l15) * DK + h * 32 + quad * 8,
                 &Ks[0][(wave * 2 + h) * 512]);
        gl2lds16(Vb + (wave * 16 + l15) * SEQ + h * 32 + quad * 8,
                 &Vs[0][(wave * 2 + h) * 512]);
    }

#pragma unroll 1
    for (int c = 0; c < nch; ++c) {
        int k0 = c * 64;
        int cur = c & 1;
        CFENCE(); __builtin_amdgcn_s_barrier(); CFENCE();   // WAR: c-1 reads done
        if (c + 1 < nch) {
            int k1 = k0 + 64;
#pragma unroll
            for (int h = 0; h < 2; ++h) {
                gl2lds16(Kb + (k1 + wave * 16 + l15) * DK + h * 32 + quad * 8,
                         &Ks[cur ^ 1][(wave * 2 + h) * 512]);
                gl2lds16(Vb + (wave * 16 + l15) * SEQ + k1 + h * 32 + quad * 8,
                         &Vs[cur ^ 1][(wave * 2 + h) * 512]);
            }
            asm volatile("s_waitcnt vmcnt(4)" ::: "memory");  // chunk c landed
        } else {
            asm volatile("s_waitcnt vmcnt(0)" ::: "memory");
        }
        CFENCE(); __builtin_amdgcn_s_barrier(); CFENCE();   // RAW: all waves staged
        if (k0 > qmax) continue;  // fully-masked chunk for this wave

        const u16* Kcur = &Ks[cur][0];
        const u16* Vcur = &Vs[cur][0];

        // S^T[key][q] = K.Q^T
        f32x4 s[4][2];
#pragma unroll
        for (int mf = 0; mf < 4; ++mf) {
            bf16x8 kf0 = *reinterpret_cast<const bf16x8*>(Kcur + (mf * 2 + 0) * 512 + lane * 8);
            bf16x8 kf1 = *reinterpret_cast<const bf16x8*>(Kcur + (mf * 2 + 1) * 512 + lane * 8);
#pragma unroll
            for (int nf = 0; nf < 2; ++nf) {
                f32x4 z = (f32x4){0.f, 0.f, 0.f, 0.f};
                z = __builtin_amdgcn_mfma_f32_16x16x32_bf16(kf0, qf[nf][0], z, 0, 0, 0);
                z = __builtin_amdgcn_mfma_f32_16x16x32_bf16(kf1, qf[nf][1], z, 0, 0, 0);
                s[mf][nf] = z;
            }
        }
        // mask iff chunk's max key exceeds wave's MIN q row
        if (k0 + 63 > q0w) {
#pragma unroll
            for (int mf = 0; mf < 4; ++mf) {
                int key = k0 + mf * 16 + quad * 4;
#pragma unroll
                for (int nf = 0; nf < 2; ++nf) {
                    int q = q0w + nf * 16 + l15;
#pragma unroll
                    for (int r = 0; r < 4; ++r)
                        if (key + r > q) s[mf][nf][r] = -__builtin_inff();
                }
            }
        }
        // p = exp2(s); pack 4 consecutive keys per ushort4 into P[q][key]
#pragma unroll
        for (int mf = 0; mf < 4; ++mf)
#pragma unroll
            for (int nf = 0; nf < 2; ++nf) {
                float p0 = __builtin_amdgcn_exp2f(s[mf][nf][0]);
                float p1 = __builtin_amdgcn_exp2f(s[mf][nf][1]);
                float p2 = __builtin_amdgcn_exp2f(s[mf][nf][2]);
                float p3 = __builtin_amdgcn_exp2f(s[mf][nf][3]);
                lsum[nf] += (p0 + p1) + (p2 + p3);
                ushort4 pk;
                pk.x = f2bf(p0); pk.y = f2bf(p1); pk.z = f2bf(p2); pk.w = f2bf(p3);
                *reinterpret_cast<ushort4*>(
                    Pw + (nf * 16 + l15) * PSTR + mf * 16 + quad * 4) = pk;
            }
        __asm__ volatile("s_waitcnt lgkmcnt(0)" ::: "memory"); // wave-private P RAW
        bf16x8 pa[2][2];
#pragma unroll
        for (int ma = 0; ma < 2; ++ma)
#pragma unroll
            for (int h = 0; h < 2; ++h)
                pa[ma][h] = *reinterpret_cast<const bf16x8*>(
                    Pw + (ma * 16 + l15) * PSTR + h * 32 + quad * 8);
#pragma unroll
        for (int nf = 0; nf < 4; ++nf) {
            bf16x8 vf0 = *reinterpret_cast<const bf16x8*>(Vcur + (nf * 2 + 0) * 512 + lane * 8);
            bf16x8 vf1 = *reinterpret_cast<const bf16x8*>(Vcur + (nf * 2 + 1) * 512 + lane * 8);
#pragma unroll
            for (int ma = 0; ma < 2; ++ma) {
                o[ma][nf] = __builtin_amdgcn_mfma_f32_16x16x32_bf16(pa[ma][0], vf0, o[ma][nf], 0, 0, 0);
                o[ma][nf] = __builtin_amdgcn_mfma_f32_16x16x32_bf16(pa[ma][1], vf1, o[ma][nf], 0, 0, 0);
            }
        }
    }
    lsum[0] += __shfl_xor(lsum[0], 16);
    lsum[0] += __shfl_xor(lsum[0], 32);
    lsum[1] += __shfl_xor(lsum[1], 16);
    lsum[1] += __shfl_xor(lsum[1], 32);
#pragma unroll
    for (int ma = 0; ma < 2; ++ma) {
#pragma unroll
        for (int r = 0; r < 4; ++r) {
            float inv = __builtin_amdgcn_rcpf(__shfl(lsum[ma], quad * 4 + r));
            int q = q0w + ma * 16 + quad * 4 + r;
#pragma unroll
            for (int nf = 0; nf < 4; ++nf) {
                int d = nf * 16 + l15;
                ao[(b * SEQ + q) * D_MODEL + hh * DK + d] = f2bf(o[ma][nf][r] * inv);
            }
        }
    }
}

extern "C" void kernel_launch(void* const* d_in, const int* in_sizes, int n_in,
                              void* d_out, int out_size, void* d_ws, size_t ws_size,
                              hipStream_t stream) {
    const float* x  = (const float*)d_in[0];
    const float* Wq = (const float*)d_in[1];
    const float* bq = (const float*)d_in[2];
    const float* Wk = (const float*)d_in[3];
    const float* bk = (const float*)d_in[4];
    const float* Wv = (const float*)d_in[5];
    const float* bv = (const float*)d_in[6];
    const float* Wo = (const float*)d_in[7];
    const float* bo = (const float*)d_in[8];
    float* out = (float*)d_out;
    char* ws = (char*)d_ws;

    const size_t XB = 16777216; // 8192*1024*2
    const size_t WB = 2097152;  // 1024*1024*2
    u16* xb  = (u16*)(ws);
    u16* wqb = (u16*)(ws + XB);
    u16* wkb = (u16*)(ws + XB + WB);
    u16* wvb = (u16*)(ws + XB + 2 * WB);
    u16* wob = (u16*)(ws + XB + 3 * WB);
    u16* qb  = (u16*)(ws + XB + 4 * WB);
    u16* kb  = (u16*)(ws + 2 * XB + 4 * WB);
    u16* vtb = (u16*)(ws + 3 * XB + 4 * WB);
    u16* ab  = (u16*)(ws + 4 * XB + 4 * WB);

    cvt_kernel<<<8192, 256, 0, stream>>>(x, xb, 2097152);
    cvt4_kernel<<<dim3(1024, 4), 256, 0, stream>>>(Wq, Wk, Wv, Wo,
                                                   wqb, wkb, wvb, wob, 262144);

    qkv_gemm256<<<dim3(32, 4, 3), 512, 0, stream>>>(xb, wqb, wkb, wvb, bq, bk, bv,
                                                    qb, kb, vtb);
    attn_kernel<<<dim3(16, 64), 256, 0, stream>>>(qb, kb, vtb, ab);
    out_gemm<<<dim3(64, 8), 256, 0, stream>>>(ab, wob, bo, out);
}

// Round 9
// 269.218 us; speedup vs baseline: 1.1473x; 1.1473x over previous
//
#include <hip/hip_runtime.h>
#include <hip/hip_bf16.h>
#include <stdint.h>

#define D_MODEL 1024
#define SEQ     2048
#define NH      16
#define DK      64
#define PSTR    72   // P LDS row stride (u16); 144B row = 16B-aligned

typedef __bf16 bf16x8 __attribute__((ext_vector_type(8)));
typedef float  f32x4  __attribute__((ext_vector_type(4)));
typedef unsigned short u16;

#define CFENCE() asm volatile("" ::: "memory")

__device__ __forceinline__ u16 f2bf(float f) {
    uint32_t u = __float_as_uint(f);
    u += 0x7FFFu + ((u >> 16) & 1u);
    return (u16)(u >> 16);
}

// async global->LDS, 16B per lane; lds dest = uniform base + lane*16 (m104)
__device__ __forceinline__ void gl2lds16(const u16* g, u16* l) {
    __builtin_amdgcn_global_load_lds(
        (const __attribute__((address_space(1))) uint32_t*)g,
        (__attribute__((address_space(3))) uint32_t*)l, 16, 0, 0);
}

__global__ __launch_bounds__(256) void cvt_kernel(const float* __restrict__ src,
                                                  u16* __restrict__ dst, int n4) {
    int i = blockIdx.x * blockDim.x + threadIdx.x;
    if (i >= n4) return;
    float4 v = reinterpret_cast<const float4*>(src)[i];
    ushort4 o;
    o.x = f2bf(v.x); o.y = f2bf(v.y); o.z = f2bf(v.z); o.w = f2bf(v.w);
    reinterpret_cast<ushort4*>(dst)[i] = o;
}

__global__ __launch_bounds__(256) void cvt4_kernel(
    const float* __restrict__ s0, const float* __restrict__ s1,
    const float* __restrict__ s2, const float* __restrict__ s3,
    u16* __restrict__ d0, u16* __restrict__ d1,
    u16* __restrict__ d2, u16* __restrict__ d3, int n4) {
    int z = blockIdx.y;
    const float* s = (z == 0) ? s0 : (z == 1) ? s1 : (z == 2) ? s2 : s3;
    u16* d = (z == 0) ? d0 : (z == 1) ? d1 : (z == 2) ? d2 : d3;
    int i = blockIdx.x * blockDim.x + threadIdx.x;
    if (i >= n4) return;
    float4 v = reinterpret_cast<const float4*>(s)[i];
    ushort4 o;
    o.x = f2bf(v.x); o.y = f2bf(v.y); o.z = f2bf(v.z); o.w = f2bf(v.w);
    reinterpret_cast<ushort4*>(d)[i] = o;
}

// ---------------------------------------------------------------------------
// 128x128 tile GEMM body (legacy 2-barrier structure) — still used by out_gemm.
// ---------------------------------------------------------------------------
__device__ __forceinline__ void gemm128_body(const u16* __restrict__ Ag,
                                             const u16* __restrict__ Bg,
                                             u16* As, u16* Bs, f32x4 acc[4][4]) {
    const int K = D_MODEL;
    int tid = threadIdx.x, wave = tid >> 6, lane = tid & 63;
    int l15 = lane & 15, quad = lane >> 4;
    int srow = lane >> 2;            // 0..15
    int scol = (lane & 3) * 8;       // 0,8,16,24
    int arg4 = (wave >> 1) * 4;      // A row-group base (16-row units)
    int brg4 = (wave & 1) * 4;
#pragma unroll 1
    for (int kc = 0; kc < K; kc += 64) {
        __syncthreads();             // WAR: prev compute's reads done everywhere
#pragma unroll
        for (int j = 0; j < 4; ++j) {
            int p = wave * 4 + j;    // page 0..15
            int rg = p >> 1, h = p & 1;
            int row = rg * 16 + srow;
            int col = kc + h * 32 + scol;
            gl2lds16(Ag + row * K + col, As + p * 512);
            gl2lds16(Bg + row * K + col, Bs + p * 512);
        }
        __syncthreads();             // RAW: all stages landed (vmcnt drained)
#pragma unroll
        for (int h = 0; h < 2; ++h) {
            bf16x8 af[4], bfr[4];
#pragma unroll
            for (int s = 0; s < 4; ++s) {
                af[s]  = *reinterpret_cast<const bf16x8*>(
                    As + ((arg4 + s) * 2 + h) * 512 + l15 * 32 + quad * 8);
                bfr[s] = *reinterpret_cast<const bf16x8*>(
                    Bs + ((brg4 + s) * 2 + h) * 512 + l15 * 32 + quad * 8);
            }
#pragma unroll
            for (int ms = 0; ms < 4; ++ms)
#pragma unroll
                for (int ns = 0; ns < 4; ++ns)
                    acc[ms][ns] = __builtin_amdgcn_mfma_f32_16x16x32_bf16(
                        af[ms], bfr[ns], acc[ms][ns], 0, 0, 0);
        }
    }
}

// ---------------------------------------------------------------------------
// QKV projection — UNCHANGED from R6 (measured best: 89.5us, WRITE=48MiB
// ideal). 256x256 tile, 8 waves, 4-phase/K-tile, R3 stage map, counted
// vmcnt(2), both-sides swizzle, coalesced LDS-transpose epilogue.
// ---------------------------------------------------------------------------
__device__ __forceinline__ void stage_half(const u16* __restrict__ gb, u16* ls,
                                           int w2, int srow, int scol) {
#pragma unroll
    for (int i = 0; i < 2; ++i)
        gl2lds16(gb + ((w2 + i) * 8 + srow) * D_MODEL + scol,
                 ls + (w2 + i) * 512);
}

__global__ __launch_bounds__(512, 2) void qkv_gemm256(
    const u16* __restrict__ xb,
    const u16* __restrict__ Wq, const u16* __restrict__ Wk, const u16* __restrict__ Wv,
    const float* __restrict__ bq, const float* __restrict__ bk, const float* __restrict__ bv,
    u16* __restrict__ qo, u16* __restrict__ ko, u16* __restrict__ vto) {
    __shared__ __align__(16) u16 smA[2][2][8192];   // [buf][half][128*64]
    __shared__ __align__(16) u16 smB[2][2][8192];
    int z = blockIdx.z;
    const u16* W = (z == 0) ? Wq : (z == 1) ? Wk : Wv;
    const float* bias = (z == 0) ? bq : (z == 1) ? bk : bv;
    int tid = threadIdx.x;
    int lane = tid & 63, wave = tid >> 6;
    int l15 = lane & 15, quad = lane >> 4;
    int wr = wave >> 2, wc = wave & 3;       // 2 x 4 wave grid
    int w2 = wave * 2;
    const u16* Abase = xb + (size_t)blockIdx.x * 256 * D_MODEL;
    const u16* Bbase = W + (size_t)blockIdx.y * 256 * D_MODEL;

    int srow = lane >> 3;                        // row within 8-row page
    int scol = ((lane & 7) ^ (lane >> 3)) * 8;   // inverse-swizzled global col
    int xb_ = (l15 & 7) << 4;                    // byte-domain XOR
    int c0 = ((quad * 16) ^ xb_) >> 1;           // u16 col offset, ks=0
    int c1 = ((64 + quad * 16) ^ xb_) >> 1;      // u16 col offset, ks=1
    int rb0 = (wc & 1) * 64;                     // B row base within its half

    f32x4 acc[8][4];
#pragma unroll
    for (int m = 0; m < 8; ++m)
#pragma unroll
        for (int n = 0; n < 4; ++n) acc[m][n] = (f32x4){0.f, 0.f, 0.f, 0.f};

    // prologue: tile0 complete + A0(1); keep A0(1) in flight (vmcnt(2))
    stage_half(Abase, &smA[0][0][0], w2, srow, scol);                    // A0(0)
    stage_half(Abase + 128 * D_MODEL, &smA[0][1][0], w2, srow, scol);    // A1(0)
    stage_half(Bbase, &smB[0][0][0], w2, srow, scol);                    // B0(0)
    stage_half(Bbase + 128 * D_MODEL, &smB[0][1][0], w2, srow, scol);    // B1(0)
    stage_half(Abase + 64, &smA[1][0][0], w2, srow, scol);               // A0(1)
    asm volatile("s_waitcnt vmcnt(2)" ::: "memory");
    __builtin_amdgcn_s_barrier();
    CFENCE();

#pragma unroll 1
    for (int t = 0; t < 16; ++t) {
        const int p = t & 1;
        const u16* As = &smA[p][wr][0];
        const u16* Bs = &smB[p][wc >> 1][0];
        bf16x8 af[4][2], bfr[4][2];

        // ---- P1: read af m0-3 + bfr n0-1; stage A1(t+1); mfma m0-3 x n0-1
#pragma unroll
        for (int m = 0; m < 4; ++m) {
            af[m][0] = *reinterpret_cast<const bf16x8*>(As + (m * 16 + l15) * 64 + c0);
            af[m][1] = *reinterpret_cast<const bf16x8*>(As + (m * 16 + l15) * 64 + c1);
        }
#pragma unroll
        for (int nn = 0; nn < 2; ++nn) {
            bfr[nn][0] = *reinterpret_cast<const bf16x8*>(Bs + (rb0 + nn * 16 + l15) * 64 + c0);
            bfr[nn][1] = *reinterpret_cast<const bf16x8*>(Bs + (rb0 + nn * 16 + l15) * 64 + c1);
        }
        if (t < 15) stage_half(Abase + 128 * D_MODEL + (t + 1) * 64,
                               &smA[(t + 1) & 1][1][0], w2, srow, scol);
        CFENCE(); __builtin_amdgcn_s_barrier(); CFENCE();
        __builtin_amdgcn_s_setprio(1);
#pragma unroll
        for (int m = 0; m < 4; ++m)
#pragma unroll
            for (int nn = 0; nn < 2; ++nn) {
                acc[m][nn] = __builtin_amdgcn_mfma_f32_16x16x32_bf16(af[m][0], bfr[nn][0], acc[m][nn], 0, 0, 0);
                acc[m][nn] = __builtin_amdgcn_mfma_f32_16x16x32_bf16(af[m][1], bfr[nn][1], acc[m][nn], 0, 0, 0);
            }
        __builtin_amdgcn_s_setprio(0);
        CFENCE(); __builtin_amdgcn_s_barrier(); CFENCE();

        // ---- P2: read bfr n2-3; stage B0(t+1); mfma m0-3 x n2-3
#pragma unroll
        for (int nn = 0; nn < 2; ++nn) {
            bfr[2 + nn][0] = *reinterpret_cast<const bf16x8*>(Bs + (rb0 + (2 + nn) * 16 + l15) * 64 + c0);
            bfr[2 + nn][1] = *reinterpret_cast<const bf16x8*>(Bs + (rb0 + (2 + nn) * 16 + l15) * 64 + c1);
        }
        if (t < 15) stage_half(Bbase + (t + 1) * 64,
                               &smB[(t + 1) & 1][0][0], w2, srow, scol);
        CFENCE(); __builtin_amdgcn_s_barrier(); CFENCE();
        __builtin_amdgcn_s_setprio(1);
#pragma unroll
        for (int m = 0; m < 4; ++m)
#pragma unroll
            for (int nn = 0; nn < 2; ++nn) {
                acc[m][2 + nn] = __builtin_amdgcn_mfma_f32_16x16x32_bf16(af[m][0], bfr[2 + nn][0], acc[m][2 + nn], 0, 0, 0);
                acc[m][2 + nn] = __builtin_amdgcn_mfma_f32_16x16x32_bf16(af[m][1], bfr[2 + nn][1], acc[m][2 + nn], 0, 0, 0);
            }
        __builtin_amdgcn_s_setprio(0);
        CFENCE(); __builtin_amdgcn_s_barrier(); CFENCE();

        // ---- P3: read af m4-7 (reuse regs); stage B1(t+1); mfma m4-7 x n0-1
#pragma unroll
        for (int m = 0; m < 4; ++m) {
            af[m][0] = *reinterpret_cast<const bf16x8*>(As + ((m + 4) * 16 + l15) * 64 + c0);
            af[m][1] = *reinterpret_cast<const bf16x8*>(As + ((m + 4) * 16 + l15) * 64 + c1);
        }
        if (t < 15) stage_half(Bbase + 128 * D_MODEL + (t + 1) * 64,
                               &smB[(t + 1) & 1][1][0], w2, srow, scol);
        CFENCE(); __builtin_amdgcn_s_barrier(); CFENCE();
        __builtin_amdgcn_s_setprio(1);
#pragma unroll
        for (int m = 0; m < 4; ++m)
#pragma unroll
            for (int nn = 0; nn < 2; ++nn) {
                acc[4 + m][nn] = __builtin_amdgcn_mfma_f32_16x16x32_bf16(af[m][0], bfr[nn][0], acc[4 + m][nn], 0, 0, 0);
                acc[4 + m][nn] = __builtin_amdgcn_mfma_f32_16x16x32_bf16(af[m][1], bfr[nn][1], acc[4 + m][nn], 0, 0, 0);
            }
        __builtin_amdgcn_s_setprio(0);
        CFENCE(); __builtin_amdgcn_s_barrier(); CFENCE();

        // ---- P4: no reads; stage A0(t+2); mfma m4-7 x n2-3; vmcnt; barrier
        if (t < 14) stage_half(Abase + (t + 2) * 64,
                               &smA[p][0][0], w2, srow, scol);
        CFENCE(); __builtin_amdgcn_s_barrier(); CFENCE();
        __builtin_amdgcn_s_setprio(1);
#pragma unroll
        for (int m = 0; m < 4; ++m)
#pragma unroll
            for (int nn = 0; nn < 2; ++nn) {
                acc[4 + m][2 + nn] = __builtin_amdgcn_mfma_f32_16x16x32_bf16(af[m][0], bfr[2 + nn][0], acc[4 + m][2 + nn], 0, 0, 0);
                acc[4 + m][2 + nn] = __builtin_amdgcn_mfma_f32_16x16x32_bf16(af[m][1], bfr[2 + nn][1], acc[4 + m][2 + nn], 0, 0, 0);
            }
        __builtin_amdgcn_s_setprio(0);
        if (t < 14) {
            asm volatile("s_waitcnt vmcnt(2)" ::: "memory");   // tile t+1 landed
            __builtin_amdgcn_s_barrier(); CFENCE();
        } else if (t == 14) {
            asm volatile("s_waitcnt vmcnt(0)" ::: "memory");   // tile 15 landed
            __builtin_amdgcn_s_barrier(); CFENCE();
        }
    }

    // Coalesced epilogue via per-wave LDS transpose (fully unrolled).
    int mw = blockIdx.x * 256 + wr * 128;
    int nwb = blockIdx.y * 256 + wc * 64;
    int hq = (nwb >> 6) & (NH - 1);
    const float qscale = 0.125f * 1.4426950408889634f;

    if (z != 2) {
        u16* dst = (z == 0) ? qo : ko;
        float sc = (z == 0) ? qscale : 1.0f;
        u16* tw = &smA[0][0][0] + wave * 1152;     // 16 rows x 72 u16
        float bv0 = bias[nwb + 0 * 16 + l15];
        float bv1 = bias[nwb + 1 * 16 + l15];
        float bv2 = bias[nwb + 2 * 16 + l15];
        float bv3 = bias[nwb + 3 * 16 + l15];
#pragma unroll
        for (int mf = 0; mf < 8; ++mf) {
#pragma unroll
            for (int nf = 0; nf < 4; ++nf) {
                int c = nf * 16 + l15;
                float bv_ = (nf == 0) ? bv0 : (nf == 1) ? bv1 : (nf == 2) ? bv2 : bv3;
#pragma unroll
                for (int r = 0; r < 4; ++r) {
                    int w = quad * 4 + r;
                    tw[w * 72 + (((c >> 3) ^ (w & 7)) << 3) + (c & 7)] =
                        f2bf((acc[mf][nf][r] + bv_) * sc);
                }
            }
            asm volatile("s_waitcnt lgkmcnt(0)" ::: "memory");
#pragma unroll
            for (int i = 0; i < 2; ++i) {
                int w = i * 8 + (lane >> 3);
                bf16x8 vv = *reinterpret_cast<const bf16x8*>(
                    tw + w * 72 + (((lane & 7) ^ (w & 7)) << 3));
                int sg = mw + mf * 16 + w;
                int b = sg >> 11, ss = sg & (SEQ - 1);
                *reinterpret_cast<bf16x8*>(
                    &dst[((b * NH + hq) * SEQ + ss) * DK + (lane & 7) * 8]) = vv;
            }
            asm volatile("s_waitcnt lgkmcnt(0)" ::: "memory");  // WAR before next mf
        }
    } else {
        u16* tw = &smA[0][0][0] + wave * 4608;     // 64 rows x 72 u16
        float bv0 = bias[nwb + 0 * 16 + l15];
        float bv1 = bias[nwb + 1 * 16 + l15];
        float bv2 = bias[nwb + 2 * 16 + l15];
        float bv3 = bias[nwb + 3 * 16 + l15];
#pragma unroll
        for (int half = 0; half < 2; ++half) {
#pragma unroll
            for (int mfi = 0; mfi < 4; ++mfi) {
                int mf = half * 4 + mfi;
#pragma unroll
                for (int nf = 0; nf < 4; ++nf) {
                    int w = nf * 16 + l15;              // d row
                    float bv_ = (nf == 0) ? bv0 : (nf == 1) ? bv1 : (nf == 2) ? bv2 : bv3;
                    int sl = mfi * 16 + quad * 4;       // s_local of elem 0
                    ushort4 pk;
                    pk.x = f2bf(acc[mf][nf][0] + bv_);
                    pk.y = f2bf(acc[mf][nf][1] + bv_);
                    pk.z = f2bf(acc[mf][nf][2] + bv_);
                    pk.w = f2bf(acc[mf][nf][3] + bv_);
                    *reinterpret_cast<ushort4*>(
                        tw + w * 72 + (((sl >> 3) ^ (w & 7)) << 3) + (sl & 7)) = pk;
                }
            }
            asm volatile("s_waitcnt lgkmcnt(0)" ::: "memory");
#pragma unroll
            for (int i = 0; i < 8; ++i) {
                int w = i * 8 + (lane >> 3);            // d
                bf16x8 vv = *reinterpret_cast<const bf16x8*>(
                    tw + w * 72 + (((lane & 7) ^ (w & 7)) << 3));
                int sg = mw + half * 64 + (lane & 7) * 8;
                int b = sg >> 11, ss = sg & (SEQ - 1);
                *reinterpret_cast<bf16x8*>(
                    &vto[((b * NH + hq) * DK + w) * SEQ + ss]) = vv;
            }
            asm volatile("s_waitcnt lgkmcnt(0)" ::: "memory");  // WAR before next half
        }
    }
}

// Output projection: fp32 out = A_bf16 @ Wo^T + bo  (legacy structure)
__global__ __launch_bounds__(256) void out_gemm(
    const u16* __restrict__ ab, const u16* __restrict__ Wo,
    const float* __restrict__ bo, float* __restrict__ out) {
    __shared__ __align__(16) u16 As[16 * 512], Bs[16 * 512];
    int lane = threadIdx.x & 63, wave = threadIdx.x >> 6;
    int l15 = lane & 15, quad = lane >> 4;
    int mw = blockIdx.x * 128 + (wave >> 1) * 64;
    int nw = blockIdx.y * 128 + (wave & 1) * 64;

    f32x4 acc[4][4];
#pragma unroll
    for (int ms = 0; ms < 4; ++ms)
#pragma unroll
        for (int ns = 0; ns < 4; ++ns)
            acc[ms][ns] = (f32x4){0.f, 0.f, 0.f, 0.f};

    gemm128_body(ab + blockIdx.x * 128 * D_MODEL, Wo + blockIdx.y * 128 * D_MODEL,
                 As, Bs, acc);

#pragma unroll
    for (int ns = 0; ns < 4; ++ns) {
        int n = nw + ns * 16 + l15;
        float bv_ = bo[n];
#pragma unroll
        for (int ms = 0; ms < 4; ++ms) {
            int mbase = mw + ms * 16 + quad * 4;
#pragma unroll
            for (int r = 0; r < 4; ++r)
                out[(mbase + r) * D_MODEL + n] = acc[ms][ns][r] + bv_;
        }
    }
}

// ---------------------------------------------------------------------------
// Causal flash attention — R8 (resubmitted R9: infra flake, kernel audited
// race/hang-free): 8-wave 256-row blocks + XCD-aware mapping.
//   (a) 512 thr = 8 waves x 32 q-rows = 256 rows/block; 8 tiles/bh ->
//       grid 512 blocks = EXACTLY one round at 2 blocks/CU (16 waves/CU).
//       Each staged 16KB chunk feeds 8 waves (2x amortization); 1 K-load +
//       1 V-load per wave per chunk -> counted vmcnt(2).
//   (b) XCD-aware id map (round-robin model: xcd = id%8): xcd=id&7,
//       j=id>>3, bh=xcd*8+(j&7) -> all 8 blocks of a bh on ONE XCD;
//       per-XCD K/V set = 8 bh x 512KB = 4MB = L2. T-order interleaves
//       big/small tiles: g=j>>3, T=(g&1)? g>>1 : 7-(g>>1).
//   Per-wave compute/masking/summation order identical to R7 (numerics
//   unchanged). Dbuf + {WAR bar; stage next; vmcnt(2); RAW bar} per chunk.
//   LDS: K/V dbuf 32KB + P 8x4.6KB = 68.9KB -> 2 blocks/CU.
// ---------------------------------------------------------------------------
__global__ __launch_bounds__(512, 4) void attn_kernel(
    const u16* __restrict__ Q, const u16* __restrict__ Kc,
    const u16* __restrict__ Vt, u16* __restrict__ ao) {
    __shared__ __align__(16) u16 Ks[2][8 * 512], Vs[2][8 * 512], Plds[8][32 * PSTR];
    int id = blockIdx.x;                  // 0..511
    int xcd = id & 7, j = id >> 3;        // j 0..63
    int bh = xcd * 8 + (j & 7);
    int g = j >> 3;                       // 0..7
    int T = (g & 1) ? (g >> 1) : (7 - (g >> 1));   // interleave big/small
    int lane = threadIdx.x & 63, wave = threadIdx.x >> 6;   // wave 0..7
    int l15 = lane & 15, quad = lane >> 4;
    const u16* Qb = Q + bh * (SEQ * DK);
    const u16* Kb = Kc + bh * (SEQ * DK);
    const u16* Vb = Vt + bh * (DK * SEQ);
    int b = bh >> 4, hh = bh & 15;
    u16* Pw = &Plds[wave][0];
    int wg = wave >> 1, wh = wave & 1;    // stage page decomposition

    int q0w = T * 256 + wave * 32;        // this wave's 32 q rows
    int qmax = q0w + 31;

    bf16x8 qf[2][2];
#pragma unroll
    for (int nf = 0; nf < 2; ++nf)
#pragma unroll
        for (int h = 0; h < 2; ++h)
            qf[nf][h] = *reinterpret_cast<const bf16x8*>(
                Qb + (q0w + nf * 16 + l15) * DK + h * 32 + quad * 8);

    f32x4 o[2][4];
#pragma unroll
    for (int ma = 0; ma < 2; ++ma)
#pragma unroll
        for (int nf = 0; nf < 4; ++nf)
            o[ma][nf] = (f32x4){0.f, 0.f, 0.f, 0.f};
    float lsum[2] = {0.f, 0.f};

    int nch = 4 * T + 4;

    // prologue: stage chunk 0 (wave stages K page `wave` + V page `wave`)
    gl2lds16(Kb + (wg * 16 + l15) * DK + wh * 32 + quad * 8, &Ks[0][wave * 512]);
    gl2lds16(Vb + (wg * 16 + l15) * SEQ + wh * 32 + quad * 8, &Vs[0][wave * 512]);

#pragma unroll 1
    for (int c = 0; c < nch; ++c) {
        int k0 = c * 64;
        int cur = c & 1;
        CFENCE(); __builtin_amdgcn_s_barrier(); CFENCE();   // WAR: c-1 reads done
        if (c + 1 < nch) {
            int k1 = k0 + 64;
            gl2lds16(Kb + (k1 + wg * 16 + l15) * DK + wh * 32 + quad * 8,
                     &Ks[cur ^ 1][wave * 512]);
            gl2lds16(Vb + (wg * 16 + l15) * SEQ + k1 + wh * 32 + quad * 8,
                     &Vs[cur ^ 1][wave * 512]);
            asm volatile("s_waitcnt vmcnt(2)" ::: "memory");  // chunk c landed
        } else {
            asm volatile("s_waitcnt vmcnt(0)" ::: "memory");
        }
        CFENCE(); __builtin_amdgcn_s_barrier(); CFENCE();   // RAW: all waves staged
        if (k0 > qmax) continue;  // fully-masked chunk for this wave

        const u16* Kcur = &Ks[cur][0];
        const u16* Vcur = &Vs[cur][0];

        // S^T[key][q] = K.Q^T
        f32x4 s[4][2];
#pragma unroll
        for (int mf = 0; mf < 4; ++mf) {
            bf16x8 kf0 = *reinterpret_cast<const bf16x8*>(Kcur + (mf * 2 + 0) * 512 + lane * 8);
            bf16x8 kf1 = *reinterpret_cast<const bf16x8*>(Kcur + (mf * 2 + 1) * 512 + lane * 8);
#pragma unroll
            for (int nf = 0; nf < 2; ++nf) {
                f32x4 z = (f32x4){0.f, 0.f, 0.f, 0.f};
                z = __builtin_amdgcn_mfma_f32_16x16x32_bf16(kf0, qf[nf][0], z, 0, 0, 0);
                z = __builtin_amdgcn_mfma_f32_16x16x32_bf16(kf1, qf[nf][1], z, 0, 0, 0);
                s[mf][nf] = z;
            }
        }
        // mask iff chunk's max key exceeds wave's MIN q row
        if (k0 + 63 > q0w) {
#pragma unroll
            for (int mf = 0; mf < 4; ++mf) {
                int key = k0 + mf * 16 + quad * 4;
#pragma unroll
                for (int nf = 0; nf < 2; ++nf) {
                    int q = q0w + nf * 16 + l15;
#pragma unroll
                    for (int r = 0; r < 4; ++r)
                        if (key + r > q) s[mf][nf][r] = -__builtin_inff();
                }
            }
        }
        // p = exp2(s); pack 4 consecutive keys per ushort4 into P[q][key]
#pragma unroll
        for (int mf = 0; mf < 4; ++mf)
#pragma unroll
            for (int nf = 0; nf < 2; ++nf) {
                float p0 = __builtin_amdgcn_exp2f(s[mf][nf][0]);
                float p1 = __builtin_amdgcn_exp2f(s[mf][nf][1]);
                float p2 = __builtin_amdgcn_exp2f(s[mf][nf][2]);
                float p3 = __builtin_amdgcn_exp2f(s[mf][nf][3]);
                lsum[nf] += (p0 + p1) + (p2 + p3);
                ushort4 pk;
                pk.x = f2bf(p0); pk.y = f2bf(p1); pk.z = f2bf(p2); pk.w = f2bf(p3);
                *reinterpret_cast<ushort4*>(
                    Pw + (nf * 16 + l15) * PSTR + mf * 16 + quad * 4) = pk;
            }
        __asm__ volatile("s_waitcnt lgkmcnt(0)" ::: "memory"); // wave-private P RAW
        bf16x8 pa[2][2];
#pragma unroll
        for (int ma = 0; ma < 2; ++ma)
#pragma unroll
            for (int h = 0; h < 2; ++h)
                pa[ma][h] = *reinterpret_cast<const bf16x8*>(
                    Pw + (ma * 16 + l15) * PSTR + h * 32 + quad * 8);
#pragma unroll
        for (int nf = 0; nf < 4; ++nf) {
            bf16x8 vf0 = *reinterpret_cast<const bf16x8*>(Vcur + (nf * 2 + 0) * 512 + lane * 8);
            bf16x8 vf1 = *reinterpret_cast<const bf16x8*>(Vcur + (nf * 2 + 1) * 512 + lane * 8);
#pragma unroll
            for (int ma = 0; ma < 2; ++ma) {
                o[ma][nf] = __builtin_amdgcn_mfma_f32_16x16x32_bf16(pa[ma][0], vf0, o[ma][nf], 0, 0, 0);
                o[ma][nf] = __builtin_amdgcn_mfma_f32_16x16x32_bf16(pa[ma][1], vf1, o[ma][nf], 0, 0, 0);
            }
        }
    }
    lsum[0] += __shfl_xor(lsum[0], 16);
    lsum[0] += __shfl_xor(lsum[0], 32);
    lsum[1] += __shfl_xor(lsum[1], 16);
    lsum[1] += __shfl_xor(lsum[1], 32);
#pragma unroll
    for (int ma = 0; ma < 2; ++ma) {
#pragma unroll
        for (int r = 0; r < 4; ++r) {
            float inv = __builtin_amdgcn_rcpf(__shfl(lsum[ma], quad * 4 + r));
            int q = q0w + ma * 16 + quad * 4 + r;
#pragma unroll
            for (int nf = 0; nf < 4; ++nf) {
                int d = nf * 16 + l15;
                ao[(b * SEQ + q) * D_MODEL + hh * DK + d] = f2bf(o[ma][nf][r] * inv);
            }
        }
    }
}

extern "C" void kernel_launch(void* const* d_in, const int* in_sizes, int n_in,
                              void* d_out, int out_size, void* d_ws, size_t ws_size,
                              hipStream_t stream) {
    const float* x  = (const float*)d_in[0];
    const float* Wq = (const float*)d_in[1];
    const float* bq = (const float*)d_in[2];
    const float* Wk = (const float*)d_in[3];
    const float* bk = (const float*)d_in[4];
    const float* Wv = (const float*)d_in[5];
    const float* bv = (const float*)d_in[6];
    const float* Wo = (const float*)d_in[7];
    const float* bo = (const float*)d_in[8];
    float* out = (float*)d_out;
    char* ws = (char*)d_ws;

    const size_t XB = 16777216; // 8192*1024*2
    const size_t WB = 2097152;  // 1024*1024*2
    u16* xb  = (u16*)(ws);
    u16* wqb = (u16*)(ws + XB);
    u16* wkb = (u16*)(ws + XB + WB);
    u16* wvb = (u16*)(ws + XB + 2 * WB);
    u16* wob = (u16*)(ws + XB + 3 * WB);
    u16* qb  = (u16*)(ws + XB + 4 * WB);
    u16* kb  = (u16*)(ws + 2 * XB + 4 * WB);
    u16* vtb = (u16*)(ws + 3 * XB + 4 * WB);
    u16* ab  = (u16*)(ws + 4 * XB + 4 * WB);

    cvt_kernel<<<8192, 256, 0, stream>>>(x, xb, 2097152);
    cvt4_kernel<<<dim3(1024, 4), 256, 0, stream>>>(Wq, Wk, Wv, Wo,
                                                   wqb, wkb, wvb, wob, 262144);

    qkv_gemm256<<<dim3(32, 4, 3), 512, 0, stream>>>(xb, wqb, wkb, wvb, bq, bk, bv,
                                                    qb, kb, vtb);
    attn_kernel<<<512, 512, 0, stream>>>(qb, kb, vtb, ab);
    out_gemm<<<dim3(64, 8), 256, 0, stream>>>(ab, wob, bo, out);
}